// Round 2
// baseline (1123.729 us; speedup 1.0000x reference)
//
#include <hip/hip_runtime.h>
#include <hip/hip_bf16.h>

#define B_ 64
#define N_ 4096
#define D_ 256
#define S_ 8
#define HID_ 512

typedef __attribute__((ext_vector_type(8))) short short8;
typedef __attribute__((ext_vector_type(4))) float f32x4;

__device__ inline unsigned int f2bf(float f){
  unsigned int x = __builtin_bit_cast(unsigned int, f);
  unsigned int r = x + 0x7fffu + ((x >> 16) & 1u);
  return (r >> 16);
}
__device__ inline float bf2f(unsigned int u){
  unsigned int x = (u & 0xffffu) << 16;
  return __builtin_bit_cast(float, x);
}

// ---------------- kernel W: convert wk|wv to bf16, concat rows [512][256] ----
__global__ void kW(const float* __restrict__ wk, const float* __restrict__ wv,
                   unsigned short* __restrict__ wkv){
  int i = blockIdx.x * 256 + threadIdx.x;   // 0..131071
  float v = (i < 256 * 256) ? wk[i] : wv[i - 256 * 256];
  wkv[i] = (unsigned short)f2bf(v);
}

// ---------------- kernel P: fused LN(inputs) + [k|v] projection (bf16 MFMA) --
// 256 threads (4 waves), BM=32 rows/tile, 4 tiles per block (pipelined:
// next tile's global loads are issued before the MFMA of the current tile).
// LDS layout: unit (kc*32+m) holds X[m][kc*8..kc*8+8] bf16, byte ^ ((kc&7)<<4).
// kv rows stored PRE-SWIZZLED in global: within-row byte off = (2n)^((m&7)<<4).
__global__ __launch_bounds__(256) void kP(const float* __restrict__ xin,
    const float* __restrict__ lng, const float* __restrict__ lnb,
    const unsigned short* __restrict__ wkv,
    const float* __restrict__ bk, const float* __restrict__ bv,
    unsigned short* __restrict__ kv)
{
  __shared__ __align__(16) unsigned short As[32 * 32 * 8];  // 16 KiB
  const int t = threadIdx.x;
  const int w = t >> 6, lane = t & 63;
  const int j = t & 63;                    // float4 column within row (0..63)
  const int lr = lane & 15, lg = lane >> 4;
  const long tileBase = (long)blockIdx.x * 4;

  const float4 g4 = *(const float4*)(lng + j * 4);
  const float4 b4 = *(const float4*)(lnb + j * 4);

  float4 pre[8];

  auto LOAD = [&](int tt){
    const float4* src = (const float4*)xin + (tileBase + tt) * 2048;
#pragma unroll
    for (int c = 0; c < 8; ++c) pre[c] = src[c * 256 + t];
  };

  auto LNSTORE = [&](){
#pragma unroll
    for (int c = 0; c < 8; ++c){
      float4 f = pre[c];
      float s  = f.x + f.y + f.z + f.w;
      float ss = f.x*f.x + f.y*f.y + f.z*f.z + f.w*f.w;
#pragma unroll
      for (int o = 1; o < 64; o <<= 1){ s += __shfl_xor(s, o); ss += __shfl_xor(ss, o); }
      const float mean = s * (1.f/256.f);
      const float rstd = rsqrtf(ss * (1.f/256.f) - mean * mean + 1e-5f);
      float y0 = (f.x - mean) * rstd * g4.x + b4.x;
      float y1 = (f.y - mean) * rstd * g4.y + b4.y;
      float y2 = (f.z - mean) * rstd * g4.z + b4.z;
      float y3 = (f.w - mean) * rstd * g4.w + b4.w;
      unsigned lo = f2bf(y0) | (f2bf(y1) << 16);
      unsigned hi = f2bf(y2) | (f2bf(y3) << 16);
      const int m  = c * 4 + w;            // row within tile (0..31)
      const int kc = j >> 1;               // 16B unit column (0..31)
      unsigned byte = (((unsigned)(kc * 32 + m)) << 4) + ((j & 1) << 3);
      byte ^= (unsigned)(kc & 7) << 4;
      uint2 pk; pk.x = lo; pk.y = hi;
      *(uint2*)((char*)As + byte) = pk;
    }
  };

  LOAD(0);
  LNSTORE();
  __syncthreads();

  for (int tt = 0; tt < 4; ++tt){
    if (tt < 3) LOAD(tt + 1);              // in flight during MFMA below

    const int n0 = w * 128;
    f32x4 acc[8][2];
#pragma unroll
    for (int a = 0; a < 8; ++a){
      acc[a][0] = (f32x4){0.f,0.f,0.f,0.f};
      acc[a][1] = (f32x4){0.f,0.f,0.f,0.f};
    }
#pragma unroll
    for (int ks = 0; ks < 8; ++ks){
      const int kc = ks * 4 + lg;
      short8 af[2];
#pragma unroll
      for (int mt = 0; mt < 2; ++mt){
        unsigned byte = (((unsigned)(kc * 32 + mt * 16 + lr)) << 4) ^ ((unsigned)(kc & 7) << 4);
        af[mt] = *(const short8*)((const char*)As + byte);
      }
      short8 bfr[8];
#pragma unroll
      for (int nt = 0; nt < 8; ++nt)
        bfr[nt] = *(const short8*)(wkv + (n0 + nt*16 + lr) * 256 + ks * 32 + lg * 8);
#pragma unroll
      for (int nt = 0; nt < 8; ++nt){
        acc[nt][0] = __builtin_amdgcn_mfma_f32_16x16x32_bf16(bfr[nt], af[0], acc[nt][0], 0, 0, 0);
        acc[nt][1] = __builtin_amdgcn_mfma_f32_16x16x32_bf16(bfr[nt], af[1], acc[nt][1], 0, 0, 0);
      }
    }
    // stores (pre-swizzled kv layout)
    const long mrow0 = (tileBase + tt) * 32;
#pragma unroll
    for (int nt = 0; nt < 8; ++nt){
      const int nb = n0 + nt*16 + lg*4;
      const float* bp = (nb < 256) ? (bk + nb) : (bv + (nb - 256));
      const float4 bias = *(const float4*)bp;
#pragma unroll
      for (int mt = 0; mt < 2; ++mt){
        const long m = mrow0 + mt*16 + lr;
        unsigned p0 = f2bf(acc[nt][mt][0] + bias.x) | (f2bf(acc[nt][mt][1] + bias.y) << 16);
        unsigned p1 = f2bf(acc[nt][mt][2] + bias.z) | (f2bf(acc[nt][mt][3] + bias.w) << 16);
        uint2 pk; pk.x = p0; pk.y = p1;
        unsigned off = ((unsigned)(nb * 2)) ^ (((unsigned)m & 7u) << 4);
        *(uint2*)((char*)kv + m * 1024 + off) = pk;
      }
    }
    __syncthreads();                        // all waves done reading As
    if (tt < 3){ LNSTORE(); __syncthreads(); }
  }
}

// ---------------- kernel I: slots = mu + sigma*init; q = LN(slots)@wq^T + bq -
__global__ __launch_bounds__(256) void kI(const float* __restrict__ init,
    const float* __restrict__ mu, const float* __restrict__ sig,
    const float* __restrict__ lsg, const float* __restrict__ lsb,
    const float* __restrict__ wq, const float* __restrict__ bq,
    float* __restrict__ slots, float* __restrict__ q)
{
  const int b = blockIdx.x, t = threadIdx.x;
  __shared__ float xs[S_ * D_];
  __shared__ float red[4 * S_ * 2];
  float sv[S_];
  const float muv = mu[t], sgv = sig[t];
#pragma unroll
  for (int i = 0; i < S_; ++i){
    float x = muv + sgv * init[(b*S_ + i)*D_ + t];
    sv[i] = x;
    slots[(b*S_ + i)*D_ + t] = x;
  }
  float s[S_], qq[S_];
#pragma unroll
  for (int i = 0; i < S_; ++i){ s[i] = sv[i]; qq[i] = sv[i]*sv[i]; }
#pragma unroll
  for (int o = 1; o < 64; o <<= 1){
#pragma unroll
    for (int i = 0; i < S_; ++i){ s[i] += __shfl_xor(s[i], o); qq[i] += __shfl_xor(qq[i], o); }
  }
  const int wv_ = t >> 6;
  if ((t & 63) == 0){
#pragma unroll
    for (int i = 0; i < S_; ++i){ red[(wv_*S_ + i)*2] = s[i]; red[(wv_*S_ + i)*2 + 1] = qq[i]; }
  }
  __syncthreads();
  const float g_ = lsg[t], bv_ = lsb[t];
#pragma unroll
  for (int i = 0; i < S_; ++i){
    float S0 = 0.f, Q0 = 0.f;
#pragma unroll
    for (int w2 = 0; w2 < 4; ++w2){ S0 += red[(w2*S_ + i)*2]; Q0 += red[(w2*S_ + i)*2 + 1]; }
    float mean = S0 * (1.f/256.f), var = Q0 * (1.f/256.f) - mean*mean;
    float rstd = rsqrtf(var + 1e-5f);
    xs[i*D_ + t] = (sv[i] - mean) * rstd * g_ + bv_;
  }
  __syncthreads();
  const float4* wr = (const float4*)(wq + (long)t * D_);
  float acc[S_];
#pragma unroll
  for (int i = 0; i < S_; ++i) acc[i] = 0.f;
  for (int kc = 0; kc < 64; ++kc){
    float4 wf = wr[kc];
#pragma unroll
    for (int i = 0; i < S_; ++i){
      float4 xf = *(const float4*)(xs + i*D_ + kc*4);
      acc[i] += wf.x*xf.x + wf.y*xf.y + wf.z*xf.z + wf.w*xf.w;
    }
  }
  const float bqv = bq[t];
#pragma unroll
  for (int i = 0; i < S_; ++i) q[(b*S_ + i)*D_ + t] = acc[i] + bqv;
}

// ---------------- kernel D: fused dots -> per-j softmax(+eps) -> num/den -----
// 256 thr; i_=t&7 (slot), j_=t>>3 (row in 32-batch). Double-buffered LDS slabs,
// reg-staged (loads at phase top, ds_write after PV). kv is pre-swizzled.
__global__ __launch_bounds__(256) void kD(const unsigned short* __restrict__ kv,
    const float* __restrict__ q, float* __restrict__ num, float* __restrict__ den)
{
  const int b = blockIdx.y, ch = blockIdx.x, t = threadIdx.x;
  __shared__ __align__(16) unsigned short kvs[2][32 * 512];   // 2 x 32 KiB
  __shared__ float qs[S_ * 264];
  __shared__ float sw[S_ * 36];
  __shared__ float denw[4][8];
  const int i_ = t & 7, j_ = t >> 3;       // slot, row-in-batch
  {
    const float* qb = q + (long)b * S_ * D_;
#pragma unroll
    for (int c = 0; c < 8; ++c){
      int idx = c * 256 + t;
      qs[(idx >> 8) * 264 + (idx & 255)] = qb[idx];
    }
    if (t < 32) denw[t >> 3][t & 7] = 0.f;
  }
  float acc[8] = {0.f,0.f,0.f,0.f,0.f,0.f,0.f,0.f};
  const uint4* kvb = (const uint4*)(kv + ((long)b * N_ + ch * 256) * 512);
  uint4 pre[8];
  auto LOADJB = [&](int jb){
    const uint4* s = kvb + jb * 2048;
#pragma unroll
    for (int c = 0; c < 8; ++c) pre[c] = s[c * 256 + t];
  };
  auto WRITEJB = [&](int buf){
    uint4* d = (uint4*)kvs[buf];
#pragma unroll
    for (int c = 0; c < 8; ++c) d[c * 256 + t] = pre[c];
  };

  LOADJB(0); WRITEJB(0); __syncthreads();

  for (int jb = 0; jb < 8; ++jb){
    if (jb < 7) LOADJB(jb + 1);            // in flight during dot+softmax+PV
    const unsigned short* cur = kvs[jb & 1];
    // ---- dot(i_, j_) over k row j_
    float f = 0.f;
    const char* krow = (const char*)(cur + j_ * 512);
    const float* qr = qs + i_ * 264;
#pragma unroll
    for (int kc = 0; kc < 32; ++kc){
      unsigned byte = ((unsigned)kc * 16) ^ (((unsigned)j_ & 7u) << 4);
      uint4 u4 = *(const uint4*)(krow + byte);
      float4 qa = *(const float4*)(qr + kc * 8);
      float4 qb2 = *(const float4*)(qr + kc * 8 + 4);
      f += bf2f(u4.x) * qa.x + bf2f(u4.x >> 16) * qa.y
         + bf2f(u4.y) * qa.z + bf2f(u4.y >> 16) * qa.w;
      f += bf2f(u4.z) * qb2.x + bf2f(u4.z >> 16) * qb2.y
         + bf2f(u4.w) * qb2.z + bf2f(u4.w >> 16) * qb2.w;
    }
    f *= 0.0625f;                           // SCALE
    // ---- softmax over slots: 8 adjacent lanes (i_)
    float m2 = f;
#pragma unroll
    for (int o = 1; o < 8; o <<= 1) m2 = fmaxf(m2, __shfl_xor(m2, o));
    float e = __expf(f - m2), sum = e;
#pragma unroll
    for (int o = 1; o < 8; o <<= 1) sum += __shfl_xor(sum, o);
    float wgt = e / sum + 1e-8f;
    sw[i_ * 36 + j_] = wgt;
    float dsum = wgt;
#pragma unroll
    for (int o = 8; o < 64; o <<= 1) dsum += __shfl_xor(dsum, o);
    if ((t & 63) < 8) denw[t >> 6][t & 7] += dsum;
    __syncthreads();                        // sw visible
    // ---- PV: out[i_][j_*8 .. +7]
#pragma unroll 8
    for (int jj = 0; jj < 32; ++jj){
      float wv = sw[i_ * 36 + jj];
      unsigned byte = (512u + (unsigned)j_ * 16) ^ (((unsigned)jj & 7u) << 4);
      uint4 vv = *(const uint4*)((const char*)(cur + jj * 512) + byte);
      acc[0] += wv * bf2f(vv.x); acc[1] += wv * bf2f(vv.x >> 16);
      acc[2] += wv * bf2f(vv.y); acc[3] += wv * bf2f(vv.y >> 16);
      acc[4] += wv * bf2f(vv.z); acc[5] += wv * bf2f(vv.z >> 16);
      acc[6] += wv * bf2f(vv.w); acc[7] += wv * bf2f(vv.w >> 16);
    }
    if (jb < 7) WRITEJB((jb + 1) & 1);      // vmcnt wait lands here (late)
    __syncthreads();
  }
  float* np = num + ((long)b * S_ + i_) * D_ + j_ * 8;
#pragma unroll
  for (int u = 0; u < 8; ++u) atomicAdd(np + u, acc[u]);
  if (t < 8) atomicAdd(den + b * S_ + t, denw[0][t] + denw[1][t] + denw[2][t] + denw[3][t]);
}

// ---------------- kernel S: updates=num/den -> GRU -> MLP -> (q or d_out) ----
__device__ inline void stats2(const float v[2], float* red, int t, float* mean, float* rstd){
  float s[2], q2[2];
#pragma unroll
  for (int ii = 0; ii < 2; ++ii){ s[ii] = v[ii]; q2[ii] = v[ii]*v[ii]; }
#pragma unroll
  for (int o = 1; o < 64; o <<= 1){
#pragma unroll
    for (int ii = 0; ii < 2; ++ii){ s[ii] += __shfl_xor(s[ii], o); q2[ii] += __shfl_xor(q2[ii], o); }
  }
  const int wv = t >> 6;
  if ((t & 63) == 0){
#pragma unroll
    for (int ii = 0; ii < 2; ++ii){ red[(wv*2 + ii)*2] = s[ii]; red[(wv*2 + ii)*2 + 1] = q2[ii]; }
  }
  __syncthreads();
#pragma unroll
  for (int ii = 0; ii < 2; ++ii){
    float S0 = 0.f, Q0 = 0.f;
#pragma unroll
    for (int w2 = 0; w2 < 4; ++w2){ S0 += red[(w2*2 + ii)*2]; Q0 += red[(w2*2 + ii)*2 + 1]; }
    float m = S0 * (1.f/256.f);
    float var = Q0 * (1.f/256.f) - m*m;
    mean[ii] = m; rstd[ii] = rsqrtf(var + 1e-5f);
  }
  __syncthreads();
}

__global__ __launch_bounds__(256) void kS(
    const float* __restrict__ num, const float* __restrict__ den,
    const float* __restrict__ slots_in,
    const float* __restrict__ w_ih, const float* __restrict__ b_ih,
    const float* __restrict__ w_hh, const float* __restrict__ b_hh,
    const float* __restrict__ w1, const float* __restrict__ b1,
    const float* __restrict__ w2, const float* __restrict__ b2,
    const float* __restrict__ fg, const float* __restrict__ fb,
    const float* __restrict__ lsg, const float* __restrict__ lsb,
    const float* __restrict__ wq, const float* __restrict__ bq,
    float* __restrict__ outp, float* __restrict__ qout, int write_q)
{
  const int blk = blockIdx.x;               // 0..255
  const int b = blk >> 2, i0 = (blk & 3) * 2;
  const int t = threadIdx.x;
  __shared__ float us[2 * D_], hs[2 * D_], xs2[2 * D_];
  __shared__ float h2s[2 * HID_];
  __shared__ float red[4 * 2 * 2];
  const long base = (long)(b * S_ + i0) * D_;
  float hreg[2];
#pragma unroll
  for (int ii = 0; ii < 2; ++ii){
    float dv = den[b * S_ + i0 + ii];
    float u = num[base + ii*D_ + t] / dv;
    float h = slots_in[base + ii*D_ + t];
    us[ii*D_ + t] = u; hs[ii*D_ + t] = h; hreg[ii] = h;
  }
  __syncthreads();
  float gi_[3][2] = {{0,0},{0,0},{0,0}};
  float gh_[3][2] = {{0,0},{0,0},{0,0}};
  {
    const float4* wi0 = (const float4*)(w_ih + (long)t * D_);
    const float4* wi1 = (const float4*)(w_ih + (long)(256 + t) * D_);
    const float4* wi2 = (const float4*)(w_ih + (long)(512 + t) * D_);
    const float4* wh0 = (const float4*)(w_hh + (long)t * D_);
    const float4* wh1 = (const float4*)(w_hh + (long)(256 + t) * D_);
    const float4* wh2 = (const float4*)(w_hh + (long)(512 + t) * D_);
    for (int kc = 0; kc < 64; ++kc){
      float4 a0 = wi0[kc], a1 = wi1[kc], a2 = wi2[kc];
      float4 c0 = wh0[kc], c1 = wh1[kc], c2 = wh2[kc];
#pragma unroll
      for (int ii = 0; ii < 2; ++ii){
        float4 uf = *(const float4*)(us + ii*D_ + kc*4);
        float4 hf = *(const float4*)(hs + ii*D_ + kc*4);
        gi_[0][ii] += a0.x*uf.x + a0.y*uf.y + a0.z*uf.z + a0.w*uf.w;
        gi_[1][ii] += a1.x*uf.x + a1.y*uf.y + a1.z*uf.z + a1.w*uf.w;
        gi_[2][ii] += a2.x*uf.x + a2.y*uf.y + a2.z*uf.z + a2.w*uf.w;
        gh_[0][ii] += c0.x*hf.x + c0.y*hf.y + c0.z*hf.z + c0.w*hf.w;
        gh_[1][ii] += c1.x*hf.x + c1.y*hf.y + c1.z*hf.z + c1.w*hf.w;
        gh_[2][ii] += c2.x*hf.x + c2.y*hf.y + c2.z*hf.z + c2.w*hf.w;
      }
    }
  }
  const float bir = b_ih[t], biz = b_ih[256 + t], bin_ = b_ih[512 + t];
  const float bhr = b_hh[t], bhz = b_hh[256 + t], bhn = b_hh[512 + t];
  float nh[2];
#pragma unroll
  for (int ii = 0; ii < 2; ++ii){
    float r = 1.f / (1.f + __expf(-(gi_[0][ii] + bir + gh_[0][ii] + bhr)));
    float z = 1.f / (1.f + __expf(-(gi_[1][ii] + biz + gh_[1][ii] + bhz)));
    float n = tanhf(gi_[2][ii] + bin_ + r * (gh_[2][ii] + bhn));
    nh[ii] = (1.f - z) * n + z * hreg[ii];
  }
  float mean[2], rstd[2];
  stats2(nh, red, t, mean, rstd);
  const float fgv = fg[t], fbv = fb[t];
#pragma unroll
  for (int ii = 0; ii < 2; ++ii) xs2[ii*D_ + t] = (nh[ii] - mean[ii]) * rstd[ii] * fgv + fbv;
  __syncthreads();
#pragma unroll
  for (int go = 0; go < 2; ++go){
    int gi = go * 256 + t;
    const float4* wr = (const float4*)(w1 + (long)gi * D_);
    float a[2] = {0,0};
    for (int kc = 0; kc < 64; ++kc){
      float4 wf = wr[kc];
#pragma unroll
      for (int ii = 0; ii < 2; ++ii){
        float4 xf = *(const float4*)(xs2 + ii*D_ + kc*4);
        a[ii] += wf.x*xf.x + wf.y*xf.y + wf.z*xf.z + wf.w*xf.w;
      }
    }
    float bb = b1[gi];
#pragma unroll
    for (int ii = 0; ii < 2; ++ii) h2s[ii*HID_ + gi] = fmaxf(a[ii] + bb, 0.f);
  }
  __syncthreads();
  float outv[2];
  {
    const float4* wr = (const float4*)(w2 + (long)t * HID_);
    float a[2] = {0,0};
    for (int kc = 0; kc < 128; ++kc){
      float4 wf = wr[kc];
#pragma unroll
      for (int ii = 0; ii < 2; ++ii){
        float4 xf = *(const float4*)(h2s + ii*HID_ + kc*4);
        a[ii] += wf.x*xf.x + wf.y*xf.y + wf.z*xf.z + wf.w*xf.w;
      }
    }
    float bb = b2[t];
#pragma unroll
    for (int ii = 0; ii < 2; ++ii) outv[ii] = nh[ii] + a[ii] + bb;
  }
#pragma unroll
  for (int ii = 0; ii < 2; ++ii) outp[base + ii*D_ + t] = outv[ii];
  if (write_q){
    float mean2[2], rstd2[2];
    stats2(outv, red, t, mean2, rstd2);
    const float lg2 = lsg[t], lb2 = lsb[t];
#pragma unroll
    for (int ii = 0; ii < 2; ++ii) xs2[ii*D_ + t] = (outv[ii] - mean2[ii]) * rstd2[ii] * lg2 + lb2;
    __syncthreads();
    const float4* wr = (const float4*)(wq + (long)t * D_);
    float a[2] = {0,0};
    for (int kc = 0; kc < 64; ++kc){
      float4 wf = wr[kc];
#pragma unroll
      for (int ii = 0; ii < 2; ++ii){
        float4 xf = *(const float4*)(xs2 + ii*D_ + kc*4);
        a[ii] += wf.x*xf.x + wf.y*xf.y + wf.z*xf.z + wf.w*xf.w;
      }
    }
    float bb = bq[t];
#pragma unroll
    for (int ii = 0; ii < 2; ++ii) qout[base + ii*D_ + t] = a[ii] + bb;
  }
}

// ---------------- host ------------------------------------------------------
extern "C" void kernel_launch(void* const* d_in, const int* in_sizes, int n_in,
                              void* d_out, int out_size, void* d_ws, size_t ws_size,
                              hipStream_t stream)
{
  const float* inputs     = (const float*)d_in[0];
  const float* slots_init = (const float*)d_in[1];
  const float* slots_mu   = (const float*)d_in[2];
  const float* slots_sig  = (const float*)d_in[3];
  const float* wq   = (const float*)d_in[4];
  const float* bq   = (const float*)d_in[5];
  const float* wk   = (const float*)d_in[6];
  const float* bk   = (const float*)d_in[7];
  const float* wv   = (const float*)d_in[8];
  const float* bv   = (const float*)d_in[9];
  const float* w_ih = (const float*)d_in[10];
  const float* b_ih = (const float*)d_in[11];
  const float* w_hh = (const float*)d_in[12];
  const float* b_hh = (const float*)d_in[13];
  const float* w1   = (const float*)d_in[14];
  const float* b1   = (const float*)d_in[15];
  const float* w2   = (const float*)d_in[16];
  const float* b2   = (const float*)d_in[17];
  const float* lig  = (const float*)d_in[18];
  const float* lib  = (const float*)d_in[19];
  const float* lsg  = (const float*)d_in[20];
  const float* lsb  = (const float*)d_in[21];
  const float* ffg  = (const float*)d_in[22];
  const float* ffb  = (const float*)d_in[23];
  float* out = (float*)d_out;

  char* ws = (char*)d_ws;
  float* num  = (float*)(ws);                         // 524288 B
  float* den  = (float*)(ws + 524288);                // 2048 B
  float* qbuf = (float*)(ws + 526336);                // 524288 B
  float* slots= (float*)(ws + 1050624);               // 524288 B
  unsigned short* wkv = (unsigned short*)(ws + 1574912);   // 262144 B
  unsigned short* kv  = (unsigned short*)(ws + 1837056);   // 268435456 B

  kW<<<512, 256, 0, stream>>>(wk, wv, wkv);
  kP<<<2048, 256, 0, stream>>>(inputs, lig, lib, wkv, bk, bv, kv);
  kI<<<64, 256, 0, stream>>>(slots_init, slots_mu, slots_sig, lsg, lsb, wq, bq, slots, qbuf);
  for (int it = 0; it < 3; ++it){
    hipMemsetAsync(num, 0, 524288 + 2048, stream);
    kD<<<dim3(16, 64), 256, 0, stream>>>(kv, qbuf, num, den);
    float* op = (it == 2) ? out : slots;
    kS<<<256, 256, 0, stream>>>(num, den, slots, w_ih, b_ih, w_hh, b_hh,
                                w1, b1, w2, b2, ffg, ffb, lsg, lsb, wq, bq,
                                op, qbuf, (it < 2) ? 1 : 0);
  }
}

// Round 3
// 811.828 us; speedup vs baseline: 1.3842x; 1.3842x over previous
//
#include <hip/hip_runtime.h>
#include <hip/hip_bf16.h>

#define B_ 64
#define N_ 4096
#define D_ 256
#define S_ 8
#define HID_ 512
#define NCH_ 16

typedef __attribute__((ext_vector_type(8))) short short8;
typedef __attribute__((ext_vector_type(4))) float f32x4;

__device__ inline unsigned int f2bf(float f){
  unsigned int x = __builtin_bit_cast(unsigned int, f);
  unsigned int r = x + 0x7fffu + ((x >> 16) & 1u);
  return (r >> 16);
}
__device__ inline float bf2f(unsigned int u){
  unsigned int x = (u & 0xffffu) << 16;
  return __builtin_bit_cast(float, x);
}

// ---------------- kernel W: convert wk|wv to bf16, concat rows [512][256] ----
__global__ void kW(const float* __restrict__ wk, const float* __restrict__ wv,
                   unsigned short* __restrict__ wkv){
  int i = blockIdx.x * 256 + threadIdx.x;
  float v = (i < 256 * 256) ? wk[i] : wv[i - 256 * 256];
  wkv[i] = (unsigned short)f2bf(v);
}

// ---------------- kernel P: fused LN(inputs) + [k|v] projection -------------
// 512 thr (8 waves). Each wave owns a 64-col n-slice; the ENTIRE wkv B-slice
// is preloaded to registers (32 short8) so the K-loop has no global loads and
// the x-prefetch is alone in the vmcnt queue (true T14 overlap).
// 8 tiles of 32 rows per block. kv written PLAIN row-major [m][512].
__global__ __launch_bounds__(512, 2) void kP(const float* __restrict__ xin,
    const float* __restrict__ lng, const float* __restrict__ lnb,
    const unsigned short* __restrict__ wkv,
    const float* __restrict__ bk, const float* __restrict__ bv,
    unsigned short* __restrict__ kv)
{
  __shared__ __align__(16) unsigned short As[32 * 32 * 8];  // 16 KiB
  const int t = threadIdx.x;
  const int w = t >> 6, lane = t & 63;
  const int lr = lane & 15, lg = lane >> 4;
  const int n0 = w * 64;
  const int row = t >> 4;        // staging row 0..31
  const int seg = t & 15;        // 16 cols each
  const long blockRow0 = (long)blockIdx.x * 256;

  // B fragments (weights), loaded once: [ks][nt]
  short8 bfr[8][4];
#pragma unroll
  for (int ks = 0; ks < 8; ++ks)
#pragma unroll
    for (int nt = 0; nt < 4; ++nt)
      bfr[ks][nt] = *(const short8*)(wkv + (n0 + nt*16 + lr)*256 + ks*32 + lg*8);

  float4 biasr[4];
#pragma unroll
  for (int nt = 0; nt < 4; ++nt){
    int nb = n0 + nt*16 + lg*4;
    biasr[nt] = (nb < 256) ? *(const float4*)(bk + nb) : *(const float4*)(bv + nb - 256);
  }

  float4 pre[4];
  auto LOAD = [&](int tt){
    const float4* src = (const float4*)(xin + (blockRow0 + tt*32 + row) * D_) + seg * 4;
#pragma unroll
    for (int c = 0; c < 4; ++c) pre[c] = src[c];
  };

  auto LNSTORE = [&](){
    float s = 0.f, ss = 0.f;
#pragma unroll
    for (int c = 0; c < 4; ++c){
      float4 f = pre[c];
      s  += f.x + f.y + f.z + f.w;
      ss += f.x*f.x + f.y*f.y + f.z*f.z + f.w*f.w;
    }
#pragma unroll
    for (int o = 1; o < 16; o <<= 1){ s += __shfl_xor(s, o); ss += __shfl_xor(ss, o); }
    const float mean = s * (1.f/256.f);
    const float rstd = rsqrtf(ss * (1.f/256.f) - mean * mean + 1e-5f);
#pragma unroll
    for (int u = 0; u < 2; ++u){
      float4 g0 = *(const float4*)(lng + seg*16 + u*8);
      float4 g1 = *(const float4*)(lng + seg*16 + u*8 + 4);
      float4 b0 = *(const float4*)(lnb + seg*16 + u*8);
      float4 b1 = *(const float4*)(lnb + seg*16 + u*8 + 4);
      float4 fa = pre[u*2], fb = pre[u*2 + 1];
      unsigned q0 = f2bf((fa.x-mean)*rstd*g0.x + b0.x) | (f2bf((fa.y-mean)*rstd*g0.y + b0.y) << 16);
      unsigned q1 = f2bf((fa.z-mean)*rstd*g0.z + b0.z) | (f2bf((fa.w-mean)*rstd*g0.w + b0.w) << 16);
      unsigned q2 = f2bf((fb.x-mean)*rstd*g1.x + b1.x) | (f2bf((fb.y-mean)*rstd*g1.y + b1.y) << 16);
      unsigned q3 = f2bf((fb.z-mean)*rstd*g1.z + b1.z) | (f2bf((fb.w-mean)*rstd*g1.w + b1.w) << 16);
      const int kc = seg*2 + u;
      unsigned byte = (((unsigned)(kc*32 + row)) << 4) ^ (((unsigned)kc & 7u) << 4);
      uint4 pk; pk.x = q0; pk.y = q1; pk.z = q2; pk.w = q3;
      *(uint4*)((char*)As + byte) = pk;
    }
  };

  LOAD(0); LNSTORE(); __syncthreads();

  for (int tt = 0; tt < 8; ++tt){
    if (tt < 7) LOAD(tt + 1);          // only thing in the vmcnt queue

    f32x4 acc[4][2];
#pragma unroll
    for (int a = 0; a < 4; ++a){ acc[a][0] = (f32x4){0,0,0,0}; acc[a][1] = (f32x4){0,0,0,0}; }
#pragma unroll
    for (int ks = 0; ks < 8; ++ks){
      const int kc = ks*4 + lg;
      const unsigned xorm = ((unsigned)kc & 7u) << 4;
      short8 af0 = *(const short8*)((const char*)As + (((unsigned)(kc*32 + lr) << 4) ^ xorm));
      short8 af1 = *(const short8*)((const char*)As + (((unsigned)(kc*32 + 16 + lr) << 4) ^ xorm));
#pragma unroll
      for (int nt = 0; nt < 4; ++nt){
        acc[nt][0] = __builtin_amdgcn_mfma_f32_16x16x32_bf16(bfr[ks][nt], af0, acc[nt][0], 0, 0, 0);
        acc[nt][1] = __builtin_amdgcn_mfma_f32_16x16x32_bf16(bfr[ks][nt], af1, acc[nt][1], 0, 0, 0);
      }
    }
    const long m0 = blockRow0 + tt*32;
#pragma unroll
    for (int nt = 0; nt < 4; ++nt){
      const int nb = n0 + nt*16 + lg*4;
#pragma unroll
      for (int mt = 0; mt < 2; ++mt){
        const long m = m0 + mt*16 + lr;
        unsigned p0 = f2bf(acc[nt][mt][0] + biasr[nt].x) | (f2bf(acc[nt][mt][1] + biasr[nt].y) << 16);
        unsigned p1 = f2bf(acc[nt][mt][2] + biasr[nt].z) | (f2bf(acc[nt][mt][3] + biasr[nt].w) << 16);
        uint2 pk; pk.x = p0; pk.y = p1;
        *(uint2*)(kv + m * 512 + nb) = pk;
      }
    }
    __syncthreads();
    if (tt < 7){ LNSTORE(); __syncthreads(); }
  }
}

// ---------------- kernel I: slots = mu + sigma*init; q = LN(slots)@wq^T + bq -
__global__ __launch_bounds__(256) void kI(const float* __restrict__ init,
    const float* __restrict__ mu, const float* __restrict__ sig,
    const float* __restrict__ lsg, const float* __restrict__ lsb,
    const float* __restrict__ wq, const float* __restrict__ bq,
    float* __restrict__ slots, float* __restrict__ q)
{
  const int b = blockIdx.x, t = threadIdx.x;
  __shared__ float xs[S_ * D_];
  __shared__ float red[4 * S_ * 2];
  float sv[S_];
  const float muv = mu[t], sgv = sig[t];
#pragma unroll
  for (int i = 0; i < S_; ++i){
    float x = muv + sgv * init[(b*S_ + i)*D_ + t];
    sv[i] = x;
    slots[(b*S_ + i)*D_ + t] = x;
  }
  float s[S_], qq[S_];
#pragma unroll
  for (int i = 0; i < S_; ++i){ s[i] = sv[i]; qq[i] = sv[i]*sv[i]; }
#pragma unroll
  for (int o = 1; o < 64; o <<= 1){
#pragma unroll
    for (int i = 0; i < S_; ++i){ s[i] += __shfl_xor(s[i], o); qq[i] += __shfl_xor(qq[i], o); }
  }
  const int wv_ = t >> 6;
  if ((t & 63) == 0){
#pragma unroll
    for (int i = 0; i < S_; ++i){ red[(wv_*S_ + i)*2] = s[i]; red[(wv_*S_ + i)*2 + 1] = qq[i]; }
  }
  __syncthreads();
  const float g_ = lsg[t], bv_ = lsb[t];
#pragma unroll
  for (int i = 0; i < S_; ++i){
    float S0 = 0.f, Q0 = 0.f;
#pragma unroll
    for (int w2 = 0; w2 < 4; ++w2){ S0 += red[(w2*S_ + i)*2]; Q0 += red[(w2*S_ + i)*2 + 1]; }
    float mean = S0 * (1.f/256.f), var = Q0 * (1.f/256.f) - mean*mean;
    float rstd = rsqrtf(var + 1e-5f);
    xs[i*D_ + t] = (sv[i] - mean) * rstd * g_ + bv_;
  }
  __syncthreads();
  const float4* wr = (const float4*)(wq + (long)t * D_);
  float acc[S_];
#pragma unroll
  for (int i = 0; i < S_; ++i) acc[i] = 0.f;
  for (int kc = 0; kc < 64; ++kc){
    float4 wf = wr[kc];
#pragma unroll
    for (int i = 0; i < S_; ++i){
      float4 xf = *(const float4*)(xs + i*D_ + kc*4);
      acc[i] += wf.x*xf.x + wf.y*xf.y + wf.z*xf.z + wf.w*xf.w;
    }
  }
  const float bqv = bq[t];
#pragma unroll
  for (int i = 0; i < S_; ++i) q[(b*S_ + i)*D_ + t] = acc[i] + bqv;
}

// ---------------- kernel D: MFMA dots -> in-wave softmax -> VALU PV ---------
// grid (16, 64), 256 thr. No k/v LDS staging: dot A-frags read from global
// (each k byte once/block, L2), PV v reads from global (8x slot dup -> L2 hits).
// LDS: q bf16 + sw + den partials (~13 KB) -> 4 blocks/CU.
__global__ __launch_bounds__(256) void kD(const unsigned short* __restrict__ kv,
    const float* __restrict__ q, float* __restrict__ numP, float* __restrict__ denP,
    int use_atomic)
{
  const int b = blockIdx.y, ch = blockIdx.x, t = threadIdx.x;
  __shared__ __align__(16) unsigned short qs[16 * 264];
  __shared__ float sw[S_ * 132];
  __shared__ float denp[4][S_];
  const int lane = t & 63, w = t >> 6;
  const int lr = lane & 15, lg = lane >> 4;

  { // build qs (rows 0..7 = q bf16, rows 8..15 = 0)
    const int rowq = t >> 4, segq = t & 15;
    uint4 z0 = {0,0,0,0}, z1 = {0,0,0,0};
    if (rowq < 8){
      const float* qr = q + ((long)b * S_ + rowq) * D_ + segq * 16;
      float4 f0 = ((const float4*)qr)[0], f1 = ((const float4*)qr)[1];
      float4 f2 = ((const float4*)qr)[2], f3 = ((const float4*)qr)[3];
      z0.x = f2bf(f0.x)|(f2bf(f0.y)<<16); z0.y = f2bf(f0.z)|(f2bf(f0.w)<<16);
      z0.z = f2bf(f1.x)|(f2bf(f1.y)<<16); z0.w = f2bf(f1.z)|(f2bf(f1.w)<<16);
      z1.x = f2bf(f2.x)|(f2bf(f2.y)<<16); z1.y = f2bf(f2.z)|(f2bf(f2.w)<<16);
      z1.z = f2bf(f3.x)|(f2bf(f3.y)<<16); z1.w = f2bf(f3.z)|(f2bf(f3.w)<<16);
    }
    *(uint4*)(qs + rowq*264 + segq*16) = z0;
    *(uint4*)(qs + rowq*264 + segq*16 + 8) = z1;
    if (t < 32) denp[t >> 3][t & 7] = 0.f;
  }
  __syncthreads();

  short8 bq[8];
#pragma unroll
  for (int ks = 0; ks < 8; ++ks)
    bq[ks] = *(const short8*)(qs + lr*264 + ks*32 + lg*8);

  float acc[8] = {0,0,0,0,0,0,0,0};
  float denl = 0.f;
  const int i_ = t >> 5, oct = t & 31;

  auto ACC = [&](uint4 v, float wg){
    acc[0] += wg * bf2f(v.x); acc[1] += wg * bf2f(v.x >> 16);
    acc[2] += wg * bf2f(v.y); acc[3] += wg * bf2f(v.y >> 16);
    acc[4] += wg * bf2f(v.z); acc[5] += wg * bf2f(v.z >> 16);
    acc[6] += wg * bf2f(v.w); acc[7] += wg * bf2f(v.w >> 16);
  };

  for (int ph = 0; ph < 2; ++ph){
    const long j0 = (long)ch * 256 + ph * 128;
    // ---- dots (wave w owns rows w*32 .. w*32+32)
#pragma unroll
    for (int tau = 0; tau < 2; ++tau){
      const long jt = j0 + w*32 + tau*16;
      const unsigned short* kr = kv + ((long)b * N_ + jt + lr) * 512;
      f32x4 d = {0,0,0,0};
#pragma unroll
      for (int ks = 0; ks < 8; ++ks){
        short8 afk = *(const short8*)(kr + ks*32 + lg*8);
        d = __builtin_amdgcn_mfma_f32_16x16x32_bf16(afk, bq[ks], d, 0, 0, 0);
      }
#pragma unroll
      for (int r = 0; r < 4; ++r){
        float x = d[r] * 0.0625f;                     // SCALE
        float m = x;
        m = fmaxf(m, __shfl_xor(m, 1));
        m = fmaxf(m, __shfl_xor(m, 2));
        m = fmaxf(m, __shfl_xor(m, 4));
        float e = __expf(x - m);
        float ssum = e;
        ssum += __shfl_xor(ssum, 1);
        ssum += __shfl_xor(ssum, 2);
        ssum += __shfl_xor(ssum, 4);
        float wv = e / ssum + 1e-8f;
        if (lr < 8){
          sw[lr*132 + w*32 + tau*16 + lg*4 + r] = wv;
          denl += wv;
        }
      }
    }
    __syncthreads();                                   // sw ready
    // ---- PV: thread = (slot i_, d-octet oct)
    const unsigned short* vrow = kv + ((long)b * N_ + j0) * 512 + 256 + oct*8;
    const float* swr = sw + i_ * 132;
    for (int jj = 0; jj < 128; jj += 4){
      uint4 v0 = *(const uint4*)(vrow + (jj+0)*512);
      uint4 v1 = *(const uint4*)(vrow + (jj+1)*512);
      uint4 v2 = *(const uint4*)(vrow + (jj+2)*512);
      uint4 v3 = *(const uint4*)(vrow + (jj+3)*512);
      float4 w4 = *(const float4*)(swr + jj);
      ACC(v0, w4.x); ACC(v1, w4.y); ACC(v2, w4.z); ACC(v3, w4.w);
    }
    __syncthreads();                                   // before sw rewrite
  }

  denl += __shfl_xor(denl, 16);
  denl += __shfl_xor(denl, 32);
  if (lane < 8) denp[w][lane] = denl;
  __syncthreads();

  const int och = use_atomic ? 0 : ch;
  const long obase = (((long)och * B_ + b) * S_ + i_) * D_ + oct * 8;
  if (use_atomic){
#pragma unroll
    for (int u = 0; u < 8; ++u) atomicAdd(numP + obase + u, acc[u]);
    if (t < 8) atomicAdd(denP + b*S_ + t, denp[0][t] + denp[1][t] + denp[2][t] + denp[3][t]);
  } else {
    float4 a0 = {acc[0], acc[1], acc[2], acc[3]};
    float4 a1 = {acc[4], acc[5], acc[6], acc[7]};
    *(float4*)(numP + obase) = a0;
    *(float4*)(numP + obase + 4) = a1;
    if (t < 8) denP[(b*S_ + t)*NCH_ + ch] = denp[0][t] + denp[1][t] + denp[2][t] + denp[3][t];
  }
}

// ---------------- kernel S: reduce partials -> GRU -> MLP -> (q or out) -----
__device__ inline void stats2(const float v[2], float* red, int t, float* mean, float* rstd){
  float s[2], q2[2];
#pragma unroll
  for (int ii = 0; ii < 2; ++ii){ s[ii] = v[ii]; q2[ii] = v[ii]*v[ii]; }
#pragma unroll
  for (int o = 1; o < 64; o <<= 1){
#pragma unroll
    for (int ii = 0; ii < 2; ++ii){ s[ii] += __shfl_xor(s[ii], o); q2[ii] += __shfl_xor(q2[ii], o); }
  }
  const int wv = t >> 6;
  if ((t & 63) == 0){
#pragma unroll
    for (int ii = 0; ii < 2; ++ii){ red[(wv*2 + ii)*2] = s[ii]; red[(wv*2 + ii)*2 + 1] = q2[ii]; }
  }
  __syncthreads();
#pragma unroll
  for (int ii = 0; ii < 2; ++ii){
    float S0 = 0.f, Q0 = 0.f;
#pragma unroll
    for (int w2 = 0; w2 < 4; ++w2){ S0 += red[(w2*2 + ii)*2]; Q0 += red[(w2*2 + ii)*2 + 1]; }
    float m = S0 * (1.f/256.f);
    float var = Q0 * (1.f/256.f) - m*m;
    mean[ii] = m; rstd[ii] = rsqrtf(var + 1e-5f);
  }
  __syncthreads();
}

__global__ __launch_bounds__(256) void kS(
    const float* __restrict__ numP, const float* __restrict__ denP, int nch,
    const float* __restrict__ slots_in,
    const float* __restrict__ w_ih, const float* __restrict__ b_ih,
    const float* __restrict__ w_hh, const float* __restrict__ b_hh,
    const float* __restrict__ w1, const float* __restrict__ b1,
    const float* __restrict__ w2, const float* __restrict__ b2,
    const float* __restrict__ fg, const float* __restrict__ fb,
    const float* __restrict__ lsg, const float* __restrict__ lsb,
    const float* __restrict__ wq, const float* __restrict__ bq,
    float* __restrict__ outp, float* __restrict__ qout, int write_q)
{
  const int blk = blockIdx.x;
  const int b = blk >> 2, i0 = (blk & 3) * 2;
  const int t = threadIdx.x;
  __shared__ float us[2 * D_], hs[2 * D_], xs2[2 * D_];
  __shared__ float h2s[2 * HID_];
  __shared__ float red[4 * 2 * 2];
  const long base = (long)(b * S_ + i0) * D_;
  float hreg[2];
#pragma unroll
  for (int ii = 0; ii < 2; ++ii){
    float dv = 0.f, u = 0.f;
    for (int ch = 0; ch < nch; ++ch){
      dv += denP[(b*S_ + i0 + ii)*nch + ch];
      u  += numP[(((long)ch * B_ + b) * S_ + i0 + ii) * D_ + t];
    }
    u /= dv;
    float h = slots_in[base + ii*D_ + t];
    us[ii*D_ + t] = u; hs[ii*D_ + t] = h; hreg[ii] = h;
  }
  __syncthreads();
  float gi_[3][2] = {{0,0},{0,0},{0,0}};
  float gh_[3][2] = {{0,0},{0,0},{0,0}};
  {
    const float4* wi0 = (const float4*)(w_ih + (long)t * D_);
    const float4* wi1 = (const float4*)(w_ih + (long)(256 + t) * D_);
    const float4* wi2 = (const float4*)(w_ih + (long)(512 + t) * D_);
    const float4* wh0 = (const float4*)(w_hh + (long)t * D_);
    const float4* wh1 = (const float4*)(w_hh + (long)(256 + t) * D_);
    const float4* wh2 = (const float4*)(w_hh + (long)(512 + t) * D_);
    for (int kc = 0; kc < 64; ++kc){
      float4 a0 = wi0[kc], a1 = wi1[kc], a2 = wi2[kc];
      float4 c0 = wh0[kc], c1 = wh1[kc], c2 = wh2[kc];
#pragma unroll
      for (int ii = 0; ii < 2; ++ii){
        float4 uf = *(const float4*)(us + ii*D_ + kc*4);
        float4 hf = *(const float4*)(hs + ii*D_ + kc*4);
        gi_[0][ii] += a0.x*uf.x + a0.y*uf.y + a0.z*uf.z + a0.w*uf.w;
        gi_[1][ii] += a1.x*uf.x + a1.y*uf.y + a1.z*uf.z + a1.w*uf.w;
        gi_[2][ii] += a2.x*uf.x + a2.y*uf.y + a2.z*uf.z + a2.w*uf.w;
        gh_[0][ii] += c0.x*hf.x + c0.y*hf.y + c0.z*hf.z + c0.w*hf.w;
        gh_[1][ii] += c1.x*hf.x + c1.y*hf.y + c1.z*hf.z + c1.w*hf.w;
        gh_[2][ii] += c2.x*hf.x + c2.y*hf.y + c2.z*hf.z + c2.w*hf.w;
      }
    }
  }
  const float bir = b_ih[t], biz = b_ih[256 + t], bin_ = b_ih[512 + t];
  const float bhr = b_hh[t], bhz = b_hh[256 + t], bhn = b_hh[512 + t];
  float nh[2];
#pragma unroll
  for (int ii = 0; ii < 2; ++ii){
    float r = 1.f / (1.f + __expf(-(gi_[0][ii] + bir + gh_[0][ii] + bhr)));
    float z = 1.f / (1.f + __expf(-(gi_[1][ii] + biz + gh_[1][ii] + bhz)));
    float n = tanhf(gi_[2][ii] + bin_ + r * (gh_[2][ii] + bhn));
    nh[ii] = (1.f - z) * n + z * hreg[ii];
  }
  float mean[2], rstd[2];
  stats2(nh, red, t, mean, rstd);
  const float fgv = fg[t], fbv = fb[t];
#pragma unroll
  for (int ii = 0; ii < 2; ++ii) xs2[ii*D_ + t] = (nh[ii] - mean[ii]) * rstd[ii] * fgv + fbv;
  __syncthreads();
#pragma unroll
  for (int go = 0; go < 2; ++go){
    int gi = go * 256 + t;
    const float4* wr = (const float4*)(w1 + (long)gi * D_);
    float a[2] = {0,0};
    for (int kc = 0; kc < 64; ++kc){
      float4 wf = wr[kc];
#pragma unroll
      for (int ii = 0; ii < 2; ++ii){
        float4 xf = *(const float4*)(xs2 + ii*D_ + kc*4);
        a[ii] += wf.x*xf.x + wf.y*xf.y + wf.z*xf.z + wf.w*xf.w;
      }
    }
    float bb = b1[gi];
#pragma unroll
    for (int ii = 0; ii < 2; ++ii) h2s[ii*HID_ + gi] = fmaxf(a[ii] + bb, 0.f);
  }
  __syncthreads();
  float outv[2];
  {
    const float4* wr = (const float4*)(w2 + (long)t * HID_);
    float a[2] = {0,0};
    for (int kc = 0; kc < 128; ++kc){
      float4 wf = wr[kc];
#pragma unroll
      for (int ii = 0; ii < 2; ++ii){
        float4 xf = *(const float4*)(h2s + ii*HID_ + kc*4);
        a[ii] += wf.x*xf.x + wf.y*xf.y + wf.z*xf.z + wf.w*xf.w;
      }
    }
    float bb = b2[t];
#pragma unroll
    for (int ii = 0; ii < 2; ++ii) outv[ii] = nh[ii] + a[ii] + bb;
  }
#pragma unroll
  for (int ii = 0; ii < 2; ++ii) outp[base + ii*D_ + t] = outv[ii];
  if (write_q){
    float mean2[2], rstd2[2];
    stats2(outv, red, t, mean2, rstd2);
    const float lg2 = lsg[t], lb2 = lsb[t];
#pragma unroll
    for (int ii = 0; ii < 2; ++ii) xs2[ii*D_ + t] = (outv[ii] - mean2[ii]) * rstd2[ii] * lg2 + lb2;
    __syncthreads();
    const float4* wr = (const float4*)(wq + (long)t * D_);
    float a[2] = {0,0};
    for (int kc = 0; kc < 64; ++kc){
      float4 wf = wr[kc];
#pragma unroll
      for (int ii = 0; ii < 2; ++ii){
        float4 xf = *(const float4*)(xs2 + ii*D_ + kc*4);
        a[ii] += wf.x*xf.x + wf.y*xf.y + wf.z*xf.z + wf.w*xf.w;
      }
    }
    float bb = bq[t];
#pragma unroll
    for (int ii = 0; ii < 2; ++ii) qout[base + ii*D_ + t] = a[ii] + bb;
  }
}

// ---------------- host ------------------------------------------------------
extern "C" void kernel_launch(void* const* d_in, const int* in_sizes, int n_in,
                              void* d_out, int out_size, void* d_ws, size_t ws_size,
                              hipStream_t stream)
{
  const float* inputs     = (const float*)d_in[0];
  const float* slots_init = (const float*)d_in[1];
  const float* slots_mu   = (const float*)d_in[2];
  const float* slots_sig  = (const float*)d_in[3];
  const float* wq   = (const float*)d_in[4];
  const float* bq   = (const float*)d_in[5];
  const float* wk   = (const float*)d_in[6];
  const float* bk   = (const float*)d_in[7];
  const float* wv   = (const float*)d_in[8];
  const float* bv   = (const float*)d_in[9];
  const float* w_ih = (const float*)d_in[10];
  const float* b_ih = (const float*)d_in[11];
  const float* w_hh = (const float*)d_in[12];
  const float* b_hh = (const float*)d_in[13];
  const float* w1   = (const float*)d_in[14];
  const float* b1   = (const float*)d_in[15];
  const float* w2   = (const float*)d_in[16];
  const float* b2   = (const float*)d_in[17];
  const float* lig  = (const float*)d_in[18];
  const float* lib  = (const float*)d_in[19];
  const float* lsg  = (const float*)d_in[20];
  const float* lsb  = (const float*)d_in[21];
  const float* ffg  = (const float*)d_in[22];
  const float* ffb  = (const float*)d_in[23];
  float* out = (float*)d_out;

  char* ws = (char*)d_ws;
  float* qbuf  = (float*)(ws);                 // 524288
  float* slots = (float*)(ws + 524288);        // 524288
  unsigned short* wkv = (unsigned short*)(ws + 1048576);  // 262144
  const size_t base = 1310720;

  // partials mode needs: base + 8MB numP + 32KB denP + 256MB kv = 278,167,552
  const bool partials = ws_size >= (base + 8388608ULL + 32768ULL + 268435456ULL);
  float* numP; float* denP; unsigned short* kv;
  size_t zero_bytes = 0;
  if (partials){
    numP = (float*)(ws + base);
    denP = (float*)(ws + base + 8388608);
    kv   = (unsigned short*)(ws + base + 8388608 + 32768);
  } else {
    numP = (float*)(ws + base);                // 524288 (atomic, ch0 only)
    denP = (float*)(ws + base + 524288);       // 2048
    kv   = (unsigned short*)(ws + base + 526336);
    zero_bytes = 524288 + 2048;
  }
  const int nch = partials ? NCH_ : 1;
  const int use_atomic = partials ? 0 : 1;

  kW<<<512, 256, 0, stream>>>(wk, wv, wkv);
  kP<<<1024, 512, 0, stream>>>(inputs, lig, lib, wkv, bk, bv, kv);
  kI<<<64, 256, 0, stream>>>(slots_init, slots_mu, slots_sig, lsg, lsb, wq, bq, slots, qbuf);
  for (int it = 0; it < 3; ++it){
    if (use_atomic) hipMemsetAsync(numP, 0, zero_bytes, stream);
    kD<<<dim3(NCH_, B_), 256, 0, stream>>>(kv, qbuf, numP, denP, use_atomic);
    float* op = (it == 2) ? out : slots;
    kS<<<256, 256, 0, stream>>>(numP, denP, nch, slots, w_ih, b_ih, w_hh, b_hh,
                                w1, b1, w2, b2, ffg, ffb, lsg, lsb, wq, bq,
                                op, qbuf, (it < 2) ? 1 : 0);
  }
}